// Round 15
// baseline (272.086 us; speedup 1.0000x reference)
//
#include <hip/hip_runtime.h>

#define NN 4096   // H*W
#define CC 256    // channels
#define DQ 32     // d_qk
#define NB 4      // batch

typedef float        f32x4  __attribute__((ext_vector_type(4)));
typedef float        f32x16 __attribute__((ext_vector_type(16)));
typedef short        s16x4  __attribute__((ext_vector_type(4)));
typedef short        s16x8  __attribute__((ext_vector_type(8)));
typedef unsigned int u32x2  __attribute__((ext_vector_type(2)));
typedef unsigned int u32x4  __attribute__((ext_vector_type(4)));

// float -> bf16 bits, round-to-nearest-even
__device__ __forceinline__ unsigned short f2bf(float f) {
  unsigned u = __builtin_bit_cast(unsigned, f);
  u += 0x7fffu + ((u >> 16) & 1u);
  return (unsigned short)(u >> 16);
}

__device__ __forceinline__ f32x4 mfma16(s16x4 a, s16x4 b, f32x4 c) {
  return __builtin_amdgcn_mfma_f32_16x16x16bf16_1k(a, b, c, 0, 0, 0);
}
__device__ __forceinline__ f32x16 mfma32b(s16x8 a, s16x8 b, f32x16 c) {
  return __builtin_amdgcn_mfma_f32_32x32x16_bf16(a, b, c, 0, 0, 0);
}

__device__ __forceinline__ s16x4 lo4(u32x4 r) { u32x2 t = {r[0], r[1]}; return __builtin_bit_cast(s16x4, t); }
__device__ __forceinline__ s16x4 hi4(u32x4 r) { u32x2 t = {r[2], r[3]}; return __builtin_bit_cast(s16x4, t); }
__device__ __forceinline__ s16x8 bc8(u32x4 r) { return __builtin_bit_cast(s16x8, r); }

// raw v_exp_f32: scores are bounded (|s|<~8), no denormal fixups needed.
__device__ __forceinline__ float fexp2(float x) {
  float r;
  asm("v_exp_f32 %0, %1" : "=v"(r) : "v"(x));
  return r;
}

#define XLS 264   // proj LDS row stride (256 + 8 pad)

// ---------------- Kernel A: fused QKV projection (R13/R7 64-col version; R14's 32-col regressed) ----------------
// QT: [B][N][32] bf16 row-contiguous.
// KT: LANE-ORDERED [B][jt=128][kh=2][lane=64][8] bf16.
// Vm: LANE-ORDERED [B][jt=128][cq=8][kh=2][lane=64][8] bf16 (k-slot bijection).
__global__ __launch_bounds__(256)
void proj_kernel(const float* __restrict__ x,
                 const float* __restrict__ Wq, const float* __restrict__ bq,
                 const float* __restrict__ Wk, const float* __restrict__ bk,
                 const float* __restrict__ Wv, const float* __restrict__ bv,
                 unsigned short* __restrict__ QT,
                 unsigned short* __restrict__ KT,
                 unsigned short* __restrict__ Vm) {
  __shared__ unsigned short Xl[64 * XLS];
  const int tid = threadIdx.x;
  const int b   = blockIdx.y;
  const int n0  = blockIdx.x * 64;

  {
    const int n4 = (tid & 15) * 4;
    int c = tid >> 4;
    const float* xp = x + (size_t)(b * CC + c) * NN + n0 + n4;
    #pragma unroll
    for (int it = 0; it < 16; ++it) {
      f32x4 v = *reinterpret_cast<const f32x4*>(xp);
      #pragma unroll
      for (int e = 0; e < 4; ++e)
        Xl[(n4 + e) * XLS + c] = f2bf(v[e]);
      c += 16; xp += (size_t)16 * NN;
    }
  }
  __syncthreads();

  const int wave = tid >> 6;
  const int lane = tid & 63;
  const int l16  = lane & 15;
  const int g    = lane >> 4;
  const float qscale = 0.0901684400555602f;  // log2(e)/16

  const float* wrowp[5];
  float wsc[5];
  #pragma unroll
  for (int rt = 0; rt < 5; ++rt) {
    const int R0 = (wave * 5 + rt) * 16;
    const int R  = R0 + l16;
    if (R0 < 32)      { wrowp[rt] = Wq + R * CC;        wsc[rt] = qscale; }
    else if (R0 < 64) { wrowp[rt] = Wk + (R - 32) * CC; wsc[rt] = 1.0f; }
    else              { wrowp[rt] = Wv + (R - 64) * CC; wsc[rt] = 1.0f; }
  }

  f32x4 acc[5][4];
  #pragma unroll
  for (int rt = 0; rt < 5; ++rt)
    #pragma unroll
    for (int nt = 0; nt < 4; ++nt) acc[rt][nt] = (f32x4){0.f, 0.f, 0.f, 0.f};

  for (int k0 = 0; k0 < CC; k0 += 32) {
    s16x4 xb[4][2];
    #pragma unroll
    for (int nt = 0; nt < 4; ++nt) {
      const unsigned short* p = &Xl[(l16 + 16 * nt) * XLS + k0 + 8 * g];
      u32x4 raw = *reinterpret_cast<const u32x4*>(p);
      xb[nt][0] = lo4(raw);
      xb[nt][1] = hi4(raw);
    }
    #pragma unroll
    for (int rt = 0; rt < 5; ++rt) {
      const float* wp = wrowp[rt] + k0 + 8 * g;
      f32x4 w0 = *reinterpret_cast<const f32x4*>(wp);
      f32x4 w1 = *reinterpret_cast<const f32x4*>(wp + 4);
      const float sc = wsc[rt];
      s16x4 wa0, wa1;
      #pragma unroll
      for (int e = 0; e < 4; ++e) {
        wa0[e] = (short)f2bf(w0[e] * sc);
        wa1[e] = (short)f2bf(w1[e] * sc);
      }
      #pragma unroll
      for (int nt = 0; nt < 4; ++nt) {
        acc[rt][nt] = mfma16(wa0, xb[nt][0], acc[rt][nt]);
        acc[rt][nt] = mfma16(wa1, xb[nt][1], acc[rt][nt]);
      }
    }
  }

  #pragma unroll
  for (int rt = 0; rt < 5; ++rt) {
    const int R0 = (wave * 5 + rt) * 16;
    float bias_r[4];
    {
      const float* bp; float bsc;
      if (R0 < 32)      { bp = bq + R0;      bsc = qscale; }
      else if (R0 < 64) { bp = bk + R0 - 32; bsc = 1.0f; }
      else              { bp = bv + R0 - 64; bsc = 1.0f; }
      #pragma unroll
      for (int r = 0; r < 4; ++r) bias_r[r] = bp[4 * g + r] * bsc;
    }
    #pragma unroll
    for (int nt = 0; nt < 4; ++nt) {
      const int n = n0 + nt * 16 + l16;
      float v0 = acc[rt][nt][0] + bias_r[0];
      float v1 = acc[rt][nt][1] + bias_r[1];
      float v2 = acc[rt][nt][2] + bias_r[2];
      float v3 = acc[rt][nt][3] + bias_r[3];
      if (R0 < 32) {
        u32x2 pk = { (unsigned)f2bf(v0) | ((unsigned)f2bf(v1) << 16),
                     (unsigned)f2bf(v2) | ((unsigned)f2bf(v3) << 16) };
        unsigned short* dst = QT + ((size_t)b * NN + n) * DQ + R0 + 4 * g;
        *reinterpret_cast<u32x2*>(dst) = pk;
      } else if (R0 < 64) {
        const int d0     = R0 - 32 + 4 * g;
        const int kh     = d0 >> 4;
        const int g2v    = (d0 >> 3) & 1;
        const int e0     = d0 & 7;
        const int jt     = n >> 5;
        const int lane_t = (n & 31) + 32 * g2v;
        u32x2 pk = { (unsigned)f2bf(v0) | ((unsigned)f2bf(v1) << 16),
                     (unsigned)f2bf(v2) | ((unsigned)f2bf(v3) << 16) };
        unsigned short* kd = KT + (((size_t)(b * 128 + jt) * 2 + kh) * 64 + lane_t) * 8 + e0;
        *reinterpret_cast<u32x2*>(kd) = pk;
      } else {
        const int c0  = R0 - 64 + 4 * g;
        const int cq  = c0 >> 5;
        const int cl  = c0 & 31;
        const int jt  = (n0 + nt * 16) >> 5;
        const int kh  = nt & 1;
        const int g2v = (l16 >> 2) & 1;
        const int e   = (l16 & 3) | (((l16 >> 3) & 1) << 2);
        unsigned short* vd = Vm
          + ((((size_t)(b * 128 + jt) * 8 + cq) * 2 + kh) * 64 + (cl + 32 * g2v)) * 8 + e;
        vd[0]  = f2bf(v0);
        vd[8]  = f2bf(v1);
        vd[16] = f2bf(v2);
        vd[24] = f2bf(v3);
      }
    }
  }
}

// ---------------- Kernel B: flash attention, lag-2 pipeline, interleaved MFMA chains ----------------
// 4 waves = chv(2) x jq(2), 1 wave/SIMD (512-reg budget). Wave: 64 q (2 strips,
// V frags shared) x 128 c x 64 j-tiles. Iter: PV(t-2) -> SM16(t-1) -> QK(t) -> loads.
// While the wave issues the VALU softmax, the matrix pipe drains last iter's 20 MFMAs.
// PV interleaved 8-wide across accumulators (RAW distance 8); ss chains interleaved.

#define SM16(SS, L, P0_, P1_) { \
  const float p0=fexp2(SS[0]),  p1=fexp2(SS[1]),  p2=fexp2(SS[2]),  p3=fexp2(SS[3]); \
  const float p4=fexp2(SS[4]),  p5=fexp2(SS[5]),  p6=fexp2(SS[6]),  p7=fexp2(SS[7]); \
  const float p8=fexp2(SS[8]),  p9=fexp2(SS[9]),  pa=fexp2(SS[10]), pb=fexp2(SS[11]); \
  const float pc=fexp2(SS[12]), pd=fexp2(SS[13]), pe=fexp2(SS[14]), pf=fexp2(SS[15]); \
  L += (((p0+p1)+(p2+p3)) + ((p4+p5)+(p6+p7))) + (((p8+p9)+(pa+pb)) + ((pc+pd)+(pe+pf))); \
  unsigned q0,q1,q2,q3,q4,q5,q6,q7; \
  asm("v_cvt_pk_bf16_f32 %0, %1, %2" : "=v"(q0) : "v"(p0), "v"(p1)); \
  asm("v_cvt_pk_bf16_f32 %0, %1, %2" : "=v"(q1) : "v"(p2), "v"(p3)); \
  asm("v_cvt_pk_bf16_f32 %0, %1, %2" : "=v"(q2) : "v"(p4), "v"(p5)); \
  asm("v_cvt_pk_bf16_f32 %0, %1, %2" : "=v"(q3) : "v"(p6), "v"(p7)); \
  asm("v_cvt_pk_bf16_f32 %0, %1, %2" : "=v"(q4) : "v"(p8), "v"(p9)); \
  asm("v_cvt_pk_bf16_f32 %0, %1, %2" : "=v"(q5) : "v"(pa), "v"(pb)); \
  asm("v_cvt_pk_bf16_f32 %0, %1, %2" : "=v"(q6) : "v"(pc), "v"(pd)); \
  asm("v_cvt_pk_bf16_f32 %0, %1, %2" : "=v"(q7) : "v"(pe), "v"(pf)); \
  u32x4 _w0 = {q0,q1,q2,q3}, _w1 = {q4,q5,q6,q7}; \
  P0_ = bc8(_w0); P1_ = bc8(_w1); }

#define SMBOTH { SM16(ss0, l0, pa0, pa1); SM16(ss1, l1, pb0, pb1); }

// QK(t): two interleaved 2-deep ss chains (K shared across strips)
#define QK_IMPL(KA, KB) { \
  ss0 = mfma32b(bc8(KA), qf00, zz16); \
  ss1 = mfma32b(bc8(KA), qf10, zz16); \
  ss0 = mfma32b(bc8(KB), qf01, ss0); \
  ss1 = mfma32b(bc8(KB), qf11, ss1); }
#define QK(KS) QK_IMPL(KS)

// PV: 16 MFMA, 8 accumulator chains, RAW distance 8
#define PV16_IMPL(V0, V1, V2, V3, V4, V5, V6, V7) { \
  o00 = mfma32b(bc8(V0), pa0, o00); \
  o01 = mfma32b(bc8(V2), pa0, o01); \
  o02 = mfma32b(bc8(V4), pa0, o02); \
  o03 = mfma32b(bc8(V6), pa0, o03); \
  o10 = mfma32b(bc8(V0), pb0, o10); \
  o11 = mfma32b(bc8(V2), pb0, o11); \
  o12 = mfma32b(bc8(V4), pb0, o12); \
  o13 = mfma32b(bc8(V6), pb0, o13); \
  o00 = mfma32b(bc8(V1), pa1, o00); \
  o01 = mfma32b(bc8(V3), pa1, o01); \
  o02 = mfma32b(bc8(V5), pa1, o02); \
  o03 = mfma32b(bc8(V7), pa1, o03); \
  o10 = mfma32b(bc8(V1), pb1, o10); \
  o11 = mfma32b(bc8(V3), pb1, o11); \
  o12 = mfma32b(bc8(V5), pb1, o12); \
  o13 = mfma32b(bc8(V7), pb1, o13); }
#define PV16(VS) PV16_IMPL(VS)

#define LOADK_IMPL(T, KA, KB) { \
  const int _tk = ((T) < 64) ? (T) : 63; \
  const size_t _o = (size_t)_tk * 1024; \
  KA = *(const u32x4*)(Kb + _o); \
  KB = *(const u32x4*)(Kb + _o + 512); }
#define LOADK(T, KS) LOADK_IMPL(T, KS)

#define LOADV_IMPL(T, V0, V1, V2, V3, V4, V5, V6, V7) { \
  const size_t _o = (size_t)(T) * 8192; \
  V0 = *(const u32x4*)(Vb + _o); \
  V1 = *(const u32x4*)(Vb + _o + 512); \
  V2 = *(const u32x4*)(Vb + _o + 1024); \
  V3 = *(const u32x4*)(Vb + _o + 1536); \
  V4 = *(const u32x4*)(Vb + _o + 2048); \
  V5 = *(const u32x4*)(Vb + _o + 2560); \
  V6 = *(const u32x4*)(Vb + _o + 3072); \
  V7 = *(const u32x4*)(Vb + _o + 3584); }
#define LOADV(T, VS) LOADV_IMPL(T, VS)

// steady-state iter t: PV(t-2) on VS (== set t&1), SM16 -> P(t-1), QK(t) on KS,
// prefetch K(t+1) into the other K set, reload V(t) into VS (just consumed).
#define ITER_IMPL(T, V0, V1, V2, V3, V4, V5, V6, V7, KA, KB, NKA, NKB) { \
  PV16_IMPL(V0, V1, V2, V3, V4, V5, V6, V7); \
  SMBOTH; \
  QK_IMPL(KA, KB); \
  LOADK_IMPL((T) + 1, NKA, NKB); \
  LOADV_IMPL((T), V0, V1, V2, V3, V4, V5, V6, V7); }
#define ITER(T, VS, KS, NKS) ITER_IMPL(T, VS, KS, NKS)

#define KS0 kA0, kB0
#define KS1 kA1, kB1
#define VS0 va0, va1, va2, va3, va4, va5, va6, va7
#define VS1 vb0, vb1, vb2, vb3, vb4, vb5, vb6, vb7

// merge epilogue: static names only (rule #20)
#define PUBLISH_CT(S, CT, OV) { \
  _Pragma("unroll") \
  for (int r = 0; r < 16; ++r) \
    fb[(((chv * 2 + (S)) * 4 + (CT)) * 16 + r) * 64 + lane] = OV[r]; }

#define FINAL_CT(S, CT, OV, GA, I) { \
  _Pragma("unroll") \
  for (int r = 0; r < 16; ++r) { \
    const float oB = fb[(((chv * 2 + (S)) * 4 + (CT)) * 16 + r) * 64 + lane]; \
    const int   c  = chv * 128 + (CT) * 32 + (r & 3) + 8 * (r >> 2) + 4 * g2; \
    const size_t adr = ((size_t)b * CC + c) * NN + (I); \
    out[adr] = (GA) * (OV[r] + oB) + x[adr]; } }

__global__ __launch_bounds__(256, 1)
void attn_kernel(const unsigned short* __restrict__ QT,
                 const unsigned short* __restrict__ KT,
                 const unsigned short* __restrict__ Vm,
                 const float* __restrict__ x,
                 const float* __restrict__ gamma,
                 float* __restrict__ out) {
  extern __shared__ float fb[];   // 16384 o-floats + 64 l-floats

  const int tid  = threadIdx.x;
  const int wave = tid >> 6;
  const int chv  = wave & 1;     // channel half (128 c)
  const int jq   = wave >> 1;    // j-half (64 tiles each)
  const int lane = tid & 63;
  const int l31  = lane & 31;
  const int g2   = lane >> 5;

  // XCD swizzle: gid%8 -> XCD; one batch per XCD pair
  const int gid = blockIdx.x;
  const int rr  = gid & 7;
  const int qq  = gid >> 3;
  const int b   = rr >> 1;
  const int xt  = (qq << 1) | (rr & 1);
  const int ibase = xt * 64;
  const float gamma0 = gamma[0];

  // Q frags, both strips
  const unsigned short* Qb = QT + ((size_t)b * NN + ibase + l31) * DQ;
  const s16x8 qf00 = bc8(*(const u32x4*)(Qb + 8 * g2));
  const s16x8 qf01 = bc8(*(const u32x4*)(Qb + 16 + 8 * g2));
  const s16x8 qf10 = bc8(*(const u32x4*)(Qb + 32 * DQ + 8 * g2));
  const s16x8 qf11 = bc8(*(const u32x4*)(Qb + 32 * DQ + 16 + 8 * g2));

  f32x16 o00, o01, o02, o03, o10, o11, o12, o13, ss0, ss1, zz16;
  #pragma unroll
  for (int r = 0; r < 16; ++r) {
    o00[r] = 0.f; o01[r] = 0.f; o02[r] = 0.f; o03[r] = 0.f;
    o10[r] = 0.f; o11[r] = 0.f; o12[r] = 0.f; o13[r] = 0.f;
    zz16[r] = 0.f;
  }
  float l0 = 0.f, l1 = 0.f;

  const unsigned short* Kb = KT + (size_t)(b * 128 + jq * 64) * 1024 + lane * 8;
  const unsigned short* Vb = Vm + ((size_t)(b * 128 + jq * 64) * 8 + chv * 4) * 1024 + lane * 8;

  u32x4 kA0, kB0, kA1, kB1;
  u32x4 va0, va1, va2, va3, va4, va5, va6, va7;
  u32x4 vb0, vb1, vb2, vb3, vb4, vb5, vb6, vb7;
  s16x8 pa0, pa1, pb0, pb1;

  // prologue: K(0),K(1),V(0),V(1); ss(0) -> P(0); ss(1); K(2)
  LOADK(0, KS0);
  LOADK(1, KS1);
  LOADV(0, VS0);
  LOADV(1, VS1);
  QK(KS0);
  SMBOTH;          // P(0), l += tile 0
  QK(KS1);         // ss(1)
  LOADK(2, KS0);

  // steady: t = 2..63 (even uses VS0/KS0, odd VS1/KS1)
  #pragma unroll 1
  for (int tt = 1; tt < 32; ++tt) {
    const int t = 2 * tt;
    ITER(t,     VS0, KS0, KS1);
    ITER(t + 1, VS1, KS1, KS0);
  }
  // after loop: PV done through t=61; P = P(62); ss = ss(63)
  PV16(VS0);       // PV(62), V(62) in VS0
  SMBOTH;          // P(63), l += tile 63
  PV16(VS1);       // PV(63), V(63) in VS1

  // fold the two g2 halves of the denominators
  l0 += __shfl_xor(l0, 32);
  l1 += __shfl_xor(l1, 32);

  // ---- jq merge: jq=1 publishes, jq=0 finalizes ----
  if (jq == 1) {
    PUBLISH_CT(0, 0, o00);
    PUBLISH_CT(0, 1, o01);
    PUBLISH_CT(0, 2, o02);
    PUBLISH_CT(0, 3, o03);
    PUBLISH_CT(1, 0, o10);
    PUBLISH_CT(1, 1, o11);
    PUBLISH_CT(1, 2, o12);
    PUBLISH_CT(1, 3, o13);
    if (chv == 0 && g2 == 0) {
      fb[16384 + l31]      = l0;
      fb[16384 + 32 + l31] = l1;
    }
  }
  __syncthreads();
  if (jq == 0) {
    const float lB0 = fb[16384 + l31];
    const float lB1 = fb[16384 + 32 + l31];
    const float ga0 = gamma0 / (l0 + lB0);
    const float ga1 = gamma0 / (l1 + lB1);
    const int i0 = ibase + l31;
    const int i1 = ibase + 32 + l31;
    FINAL_CT(0, 0, o00, ga0, i0);
    FINAL_CT(0, 1, o01, ga0, i0);
    FINAL_CT(0, 2, o02, ga0, i0);
    FINAL_CT(0, 3, o03, ga0, i0);
    FINAL_CT(1, 0, o10, ga1, i1);
    FINAL_CT(1, 1, o11, ga1, i1);
    FINAL_CT(1, 2, o12, ga1, i1);
    FINAL_CT(1, 3, o13, ga1, i1);
  }
}

extern "C" void kernel_launch(void* const* d_in, const int* in_sizes, int n_in,
                              void* d_out, int out_size, void* d_ws, size_t ws_size,
                              hipStream_t stream) {
  const float* x     = (const float*)d_in[0];
  const float* Wq    = (const float*)d_in[1];
  const float* bq    = (const float*)d_in[2];
  const float* Wk    = (const float*)d_in[3];
  const float* bk    = (const float*)d_in[4];
  const float* Wv    = (const float*)d_in[5];
  const float* bv    = (const float*)d_in[6];
  const float* gamma = (const float*)d_in[7];
  float* out = (float*)d_out;

  unsigned short* QT = (unsigned short*)d_ws;
  unsigned short* KT = QT + (size_t)NB * NN * DQ;
  unsigned short* Vm = KT + (size_t)NB * NN * DQ;

  const int ldsB = (16384 + 64) * 4;   // 65792 B dynamic LDS for the merge
  static bool attr_set = false;
  if (!attr_set) {
    hipFuncSetAttribute((const void*)attn_kernel,
                        hipFuncAttributeMaxDynamicSharedMemorySize, ldsB);
    attr_set = true;
  }

  dim3 gridP(64, NB), blkP(256);
  proj_kernel<<<gridP, blkP, 0, stream>>>(x, Wq, bq, Wk, bk, Wv, bv, QT, KT, Vm);
  attn_kernel<<<256, 256, ldsB, stream>>>(QT, KT, Vm, x, gamma, out);
}

// Round 16
// 86.209 us; speedup vs baseline: 3.1561x; 3.1561x over previous
//
#include <hip/hip_runtime.h>

#define NN 4096   // H*W
#define CC 256    // channels
#define DQ 32     // d_qk
#define NB 4      // batch

typedef float        f32x4  __attribute__((ext_vector_type(4)));
typedef float        f32x16 __attribute__((ext_vector_type(16)));
typedef short        s16x4  __attribute__((ext_vector_type(4)));
typedef short        s16x8  __attribute__((ext_vector_type(8)));
typedef unsigned int u32x2  __attribute__((ext_vector_type(2)));
typedef unsigned int u32x4  __attribute__((ext_vector_type(4)));

// float -> bf16 bits, round-to-nearest-even
__device__ __forceinline__ unsigned short f2bf(float f) {
  unsigned u = __builtin_bit_cast(unsigned, f);
  u += 0x7fffu + ((u >> 16) & 1u);
  return (unsigned short)(u >> 16);
}

__device__ __forceinline__ f32x4 mfma16(s16x4 a, s16x4 b, f32x4 c) {
  return __builtin_amdgcn_mfma_f32_16x16x16bf16_1k(a, b, c, 0, 0, 0);
}
__device__ __forceinline__ f32x16 mfma32b(s16x8 a, s16x8 b, f32x16 c) {
  return __builtin_amdgcn_mfma_f32_32x32x16_bf16(a, b, c, 0, 0, 0);
}

__device__ __forceinline__ s16x4 lo4(u32x4 r) { u32x2 t = {r[0], r[1]}; return __builtin_bit_cast(s16x4, t); }
__device__ __forceinline__ s16x4 hi4(u32x4 r) { u32x2 t = {r[2], r[3]}; return __builtin_bit_cast(s16x4, t); }
__device__ __forceinline__ s16x8 bc8(u32x4 r) { return __builtin_bit_cast(s16x8, r); }

// raw v_exp_f32: scores are bounded (|s|<~8), no denormal fixups needed.
__device__ __forceinline__ float fexp2(float x) {
  float r;
  asm("v_exp_f32 %0, %1" : "=v"(r) : "v"(x));
  return r;
}

#define XLS 264   // proj LDS row stride (256 + 8 pad)

// ---------------- Kernel A: fused QKV projection (64-col, R7/R13-verified) ----------------
// QT: [B][N][32] bf16 row-contiguous.
// KT: LANE-ORDERED [B][jt=128][kh=2][lane=64][8] bf16.
// Vm: LANE-ORDERED [B][jt=128][cq=8][kh=2][lane=64][8] bf16 (k-slot bijection).
__global__ __launch_bounds__(256)
void proj_kernel(const float* __restrict__ x,
                 const float* __restrict__ Wq, const float* __restrict__ bq,
                 const float* __restrict__ Wk, const float* __restrict__ bk,
                 const float* __restrict__ Wv, const float* __restrict__ bv,
                 unsigned short* __restrict__ QT,
                 unsigned short* __restrict__ KT,
                 unsigned short* __restrict__ Vm) {
  __shared__ unsigned short Xl[64 * XLS];
  const int tid = threadIdx.x;
  const int b   = blockIdx.y;
  const int n0  = blockIdx.x * 64;

  {
    const int n4 = (tid & 15) * 4;
    int c = tid >> 4;
    const float* xp = x + (size_t)(b * CC + c) * NN + n0 + n4;
    #pragma unroll
    for (int it = 0; it < 16; ++it) {
      f32x4 v = *reinterpret_cast<const f32x4*>(xp);
      #pragma unroll
      for (int e = 0; e < 4; ++e)
        Xl[(n4 + e) * XLS + c] = f2bf(v[e]);
      c += 16; xp += (size_t)16 * NN;
    }
  }
  __syncthreads();

  const int wave = tid >> 6;
  const int lane = tid & 63;
  const int l16  = lane & 15;
  const int g    = lane >> 4;
  const float qscale = 0.0901684400555602f;  // log2(e)/16

  const float* wrowp[5];
  float wsc[5];
  #pragma unroll
  for (int rt = 0; rt < 5; ++rt) {
    const int R0 = (wave * 5 + rt) * 16;
    const int R  = R0 + l16;
    if (R0 < 32)      { wrowp[rt] = Wq + R * CC;        wsc[rt] = qscale; }
    else if (R0 < 64) { wrowp[rt] = Wk + (R - 32) * CC; wsc[rt] = 1.0f; }
    else              { wrowp[rt] = Wv + (R - 64) * CC; wsc[rt] = 1.0f; }
  }

  f32x4 acc[5][4];
  #pragma unroll
  for (int rt = 0; rt < 5; ++rt)
    #pragma unroll
    for (int nt = 0; nt < 4; ++nt) acc[rt][nt] = (f32x4){0.f, 0.f, 0.f, 0.f};

  for (int k0 = 0; k0 < CC; k0 += 32) {
    s16x4 xb[4][2];
    #pragma unroll
    for (int nt = 0; nt < 4; ++nt) {
      const unsigned short* p = &Xl[(l16 + 16 * nt) * XLS + k0 + 8 * g];
      u32x4 raw = *reinterpret_cast<const u32x4*>(p);
      xb[nt][0] = lo4(raw);
      xb[nt][1] = hi4(raw);
    }
    #pragma unroll
    for (int rt = 0; rt < 5; ++rt) {
      const float* wp = wrowp[rt] + k0 + 8 * g;
      f32x4 w0 = *reinterpret_cast<const f32x4*>(wp);
      f32x4 w1 = *reinterpret_cast<const f32x4*>(wp + 4);
      const float sc = wsc[rt];
      s16x4 wa0, wa1;
      #pragma unroll
      for (int e = 0; e < 4; ++e) {
        wa0[e] = (short)f2bf(w0[e] * sc);
        wa1[e] = (short)f2bf(w1[e] * sc);
      }
      #pragma unroll
      for (int nt = 0; nt < 4; ++nt) {
        acc[rt][nt] = mfma16(wa0, xb[nt][0], acc[rt][nt]);
        acc[rt][nt] = mfma16(wa1, xb[nt][1], acc[rt][nt]);
      }
    }
  }

  #pragma unroll
  for (int rt = 0; rt < 5; ++rt) {
    const int R0 = (wave * 5 + rt) * 16;
    float bias_r[4];
    {
      const float* bp; float bsc;
      if (R0 < 32)      { bp = bq + R0;      bsc = qscale; }
      else if (R0 < 64) { bp = bk + R0 - 32; bsc = 1.0f; }
      else              { bp = bv + R0 - 64; bsc = 1.0f; }
      #pragma unroll
      for (int r = 0; r < 4; ++r) bias_r[r] = bp[4 * g + r] * bsc;
    }
    #pragma unroll
    for (int nt = 0; nt < 4; ++nt) {
      const int n = n0 + nt * 16 + l16;
      float v0 = acc[rt][nt][0] + bias_r[0];
      float v1 = acc[rt][nt][1] + bias_r[1];
      float v2 = acc[rt][nt][2] + bias_r[2];
      float v3 = acc[rt][nt][3] + bias_r[3];
      if (R0 < 32) {
        u32x2 pk = { (unsigned)f2bf(v0) | ((unsigned)f2bf(v1) << 16),
                     (unsigned)f2bf(v2) | ((unsigned)f2bf(v3) << 16) };
        unsigned short* dst = QT + ((size_t)b * NN + n) * DQ + R0 + 4 * g;
        *reinterpret_cast<u32x2*>(dst) = pk;
      } else if (R0 < 64) {
        const int d0     = R0 - 32 + 4 * g;
        const int kh     = d0 >> 4;
        const int g2v    = (d0 >> 3) & 1;
        const int e0     = d0 & 7;
        const int jt     = n >> 5;
        const int lane_t = (n & 31) + 32 * g2v;
        u32x2 pk = { (unsigned)f2bf(v0) | ((unsigned)f2bf(v1) << 16),
                     (unsigned)f2bf(v2) | ((unsigned)f2bf(v3) << 16) };
        unsigned short* kd = KT + (((size_t)(b * 128 + jt) * 2 + kh) * 64 + lane_t) * 8 + e0;
        *reinterpret_cast<u32x2*>(kd) = pk;
      } else {
        const int c0  = R0 - 64 + 4 * g;
        const int cq  = c0 >> 5;
        const int cl  = c0 & 31;
        const int jt  = (n0 + nt * 16) >> 5;
        const int kh  = nt & 1;
        const int g2v = (l16 >> 2) & 1;
        const int e   = (l16 & 3) | (((l16 >> 3) & 1) << 2);
        unsigned short* vd = Vm
          + ((((size_t)(b * 128 + jt) * 8 + cq) * 2 + kh) * 64 + (cl + 32 * g2v)) * 8 + e;
        vd[0]  = f2bf(v0);
        vd[8]  = f2bf(v1);
        vd[16] = f2bf(v2);
        vd[24] = f2bf(v3);
      }
    }
  }
}

// ---------------- Kernel B: flash attention, Q=32/wave, 4 waves/SIMD target ----------------
// 512 blocks x 512 threads; block = 32 q; 8 waves = jq(2) x cs(4).
// Wave: 32 q x 64 c x 64 j-tiles. Per iter: 2 K + 4 V 1KB loads (depth-1 dbuf),
// 2 QK MFMA, 16 exp2, 8 cvt_pk, ~16 adds, 4 PV MFMA. o = 32 regs ->
// total demand ~110 < 128 -> 2 blocks/CU = 4 waves/SIMD (TLP fills R9's 26% idle).

#define SM16(SS, L, P0_, P1_) { \
  const float p0=fexp2(SS[0]),  p1=fexp2(SS[1]),  p2=fexp2(SS[2]),  p3=fexp2(SS[3]); \
  const float p4=fexp2(SS[4]),  p5=fexp2(SS[5]),  p6=fexp2(SS[6]),  p7=fexp2(SS[7]); \
  const float p8=fexp2(SS[8]),  p9=fexp2(SS[9]),  pa=fexp2(SS[10]), pb=fexp2(SS[11]); \
  const float pc=fexp2(SS[12]), pd=fexp2(SS[13]), pe=fexp2(SS[14]), pf=fexp2(SS[15]); \
  L += (((p0+p1)+(p2+p3)) + ((p4+p5)+(p6+p7))) + (((p8+p9)+(pa+pb)) + ((pc+pd)+(pe+pf))); \
  unsigned q0,q1,q2,q3,q4,q5,q6,q7; \
  asm("v_cvt_pk_bf16_f32 %0, %1, %2" : "=v"(q0) : "v"(p0), "v"(p1)); \
  asm("v_cvt_pk_bf16_f32 %0, %1, %2" : "=v"(q1) : "v"(p2), "v"(p3)); \
  asm("v_cvt_pk_bf16_f32 %0, %1, %2" : "=v"(q2) : "v"(p4), "v"(p5)); \
  asm("v_cvt_pk_bf16_f32 %0, %1, %2" : "=v"(q3) : "v"(p6), "v"(p7)); \
  asm("v_cvt_pk_bf16_f32 %0, %1, %2" : "=v"(q4) : "v"(p8), "v"(p9)); \
  asm("v_cvt_pk_bf16_f32 %0, %1, %2" : "=v"(q5) : "v"(pa), "v"(pb)); \
  asm("v_cvt_pk_bf16_f32 %0, %1, %2" : "=v"(q6) : "v"(pc), "v"(pd)); \
  asm("v_cvt_pk_bf16_f32 %0, %1, %2" : "=v"(q7) : "v"(pe), "v"(pf)); \
  u32x4 _w0 = {q0,q1,q2,q3}, _w1 = {q4,q5,q6,q7}; \
  P0_ = bc8(_w0); P1_ = bc8(_w1); }

// one-level indirection so SET_* expand BEFORE argument binding
#define LOADK_IMPL(T, KA, KB) { \
  const int _tk = ((T) < 64) ? (T) : 63; \
  const size_t _o = (size_t)_tk * 1024; \
  KA = *(const u32x4*)(Kb + _o); \
  KB = *(const u32x4*)(Kb + _o + 512); }

#define LOADV_IMPL(T, V0, V1, V2, V3) { \
  const int _tv = ((T) < 64) ? (T) : 63; \
  const size_t _o = (size_t)_tv * 8192; \
  V0 = *(const u32x4*)(Vb + _o); \
  V1 = *(const u32x4*)(Vb + _o + 512); \
  V2 = *(const u32x4*)(Vb + _o + 1024); \
  V3 = *(const u32x4*)(Vb + _o + 1536); }

// iter T: prefetch T+1 into next set, QK(T), softmax, PV(T)
#define ITER_IMPL(T, KA, KB, V0, V1, V2, V3, NKA, NKB, NV0, NV1, NV2, NV3) { \
  LOADK_IMPL((T) + 1, NKA, NKB); \
  LOADV_IMPL((T) + 1, NV0, NV1, NV2, NV3); \
  f32x16 ss = mfma32b(bc8(KA), qf0, zz16); \
  ss = mfma32b(bc8(KB), qf1, ss); \
  s16x8 P0, P1; \
  SM16(ss, l, P0, P1); \
  o0 = mfma32b(bc8(V0), P0, o0); \
  o0 = mfma32b(bc8(V1), P1, o0); \
  o1 = mfma32b(bc8(V2), P0, o1); \
  o1 = mfma32b(bc8(V3), P1, o1); \
}
#define ITER(T, SETC, SETN) ITER_IMPL(T, SETC, SETN)

#define SET_A kA0, kB0, va0, va1, va2, va3
#define SET_B kA1, kB1, vb0, vb1, vb2, vb3

#define PUBLISH_CT(CT, OV) { \
  _Pragma("unroll") \
  for (int r = 0; r < 16; ++r) \
    fb[((cs * 2 + (CT)) * 16 + r) * 64 + lane] = OV[r]; }

#define FINAL_CT(CT, OV) { \
  _Pragma("unroll") \
  for (int r = 0; r < 16; ++r) { \
    const float oB = fb[((cs * 2 + (CT)) * 16 + r) * 64 + lane]; \
    const int   c  = cs * 64 + (CT) * 32 + (r & 3) + 8 * (r >> 2) + 4 * g2; \
    const size_t adr = ((size_t)b * CC + c) * NN + i; \
    out[adr] = ga * (OV[r] + oB) + x[adr]; } }

__global__ __launch_bounds__(512)
void attn_kernel(const unsigned short* __restrict__ QT,
                 const unsigned short* __restrict__ KT,
                 const unsigned short* __restrict__ Vm,
                 const float* __restrict__ x,
                 const float* __restrict__ gamma,
                 float* __restrict__ out) {
  __shared__ float fb[8192 + 32];   // jq-merge: 8 o-vectors x 16 x 64 + 32 l

  const int tid  = threadIdx.x;
  const int wave = tid >> 6;
  const int jq   = wave >> 2;    // j-half (64 tiles each)
  const int cs   = wave & 3;     // 64-channel slice
  const int lane = tid & 63;
  const int l31  = lane & 31;
  const int g2   = lane >> 5;

  // XCD swizzle: gid%8 -> XCD; one batch per XCD pair; xt 0..127 per batch
  const int gid = blockIdx.x;
  const int rr  = gid & 7;
  const int qq  = gid >> 3;
  const int b   = rr >> 1;
  const int xt  = (qq << 1) | (rr & 1);
  const int ibase = xt * 32;
  const float gamma0 = gamma[0];

  // Q frags (32 q rows)
  const unsigned short* Qb = QT + ((size_t)b * NN + ibase + l31) * DQ;
  const s16x8 qf0 = bc8(*(const u32x4*)(Qb + 8 * g2));
  const s16x8 qf1 = bc8(*(const u32x4*)(Qb + 16 + 8 * g2));

  f32x16 o0, o1, zz16;
  #pragma unroll
  for (int r = 0; r < 16; ++r) { o0[r] = 0.f; o1[r] = 0.f; zz16[r] = 0.f; }
  float l = 0.f;

  const unsigned short* Kb = KT + (size_t)(b * 128 + jq * 64) * 1024 + lane * 8;
  const unsigned short* Vb = Vm + ((size_t)(b * 128 + jq * 64) * 8 + cs * 2) * 1024 + lane * 8;

  u32x4 kA0, kB0, va0, va1, va2, va3;
  u32x4 kA1, kB1, vb0, vb1, vb2, vb3;

  // prologue: tile 0 -> A
  LOADK_IMPL(0, kA0, kB0);
  LOADV_IMPL(0, va0, va1, va2, va3);

  #pragma unroll 1
  for (int tt = 0; tt < 32; ++tt) {
    const int t = 2 * tt;
    ITER(t,     SET_A, SET_B);
    ITER(t + 1, SET_B, SET_A);
  }

  // fold the two g2 halves of the denominator (lane's 16 j's + partner's 16)
  l += __shfl_xor(l, 32);

  // ---- jq merge: jq=1 publishes, jq=0 finalizes ----
  if (jq == 1) {
    PUBLISH_CT(0, o0);
    PUBLISH_CT(1, o1);
    if (cs == 0 && g2 == 0) fb[8192 + l31] = l;
  }
  __syncthreads();
  if (jq == 0) {
    const float lB = fb[8192 + l31];
    const float ga = gamma0 / (l + lB);
    const int i = ibase + l31;
    FINAL_CT(0, o0);
    FINAL_CT(1, o1);
  }
}

extern "C" void kernel_launch(void* const* d_in, const int* in_sizes, int n_in,
                              void* d_out, int out_size, void* d_ws, size_t ws_size,
                              hipStream_t stream) {
  const float* x     = (const float*)d_in[0];
  const float* Wq    = (const float*)d_in[1];
  const float* bq    = (const float*)d_in[2];
  const float* Wk    = (const float*)d_in[3];
  const float* bk    = (const float*)d_in[4];
  const float* Wv    = (const float*)d_in[5];
  const float* bv    = (const float*)d_in[6];
  const float* gamma = (const float*)d_in[7];
  float* out = (float*)d_out;

  unsigned short* QT = (unsigned short*)d_ws;
  unsigned short* KT = QT + (size_t)NB * NN * DQ;
  unsigned short* Vm = KT + (size_t)NB * NN * DQ;

  dim3 gridP(64, NB), blkP(256);
  proj_kernel<<<gridP, blkP, 0, stream>>>(x, Wq, bq, Wk, bk, Wv, bv, QT, KT, Vm);
  attn_kernel<<<512, 512, 0, stream>>>(QT, KT, Vm, x, gamma, out);
}

// Round 17
// 85.024 us; speedup vs baseline: 3.2001x; 1.0139x over previous
//
#include <hip/hip_runtime.h>

#define NN 4096   // H*W
#define CC 256    // channels
#define DQ 32     // d_qk
#define NB 4      // batch

typedef float        f32x4  __attribute__((ext_vector_type(4)));
typedef float        f32x16 __attribute__((ext_vector_type(16)));
typedef short        s16x4  __attribute__((ext_vector_type(4)));
typedef short        s16x8  __attribute__((ext_vector_type(8)));
typedef unsigned int u32x2  __attribute__((ext_vector_type(2)));
typedef unsigned int u32x4  __attribute__((ext_vector_type(4)));

// float -> bf16 bits, round-to-nearest-even
__device__ __forceinline__ unsigned short f2bf(float f) {
  unsigned u = __builtin_bit_cast(unsigned, f);
  u += 0x7fffu + ((u >> 16) & 1u);
  return (unsigned short)(u >> 16);
}

__device__ __forceinline__ f32x4 mfma16(s16x4 a, s16x4 b, f32x4 c) {
  return __builtin_amdgcn_mfma_f32_16x16x16bf16_1k(a, b, c, 0, 0, 0);
}
__device__ __forceinline__ f32x16 mfma32b(s16x8 a, s16x8 b, f32x16 c) {
  return __builtin_amdgcn_mfma_f32_32x32x16_bf16(a, b, c, 0, 0, 0);
}

__device__ __forceinline__ s16x4 lo4(u32x4 r) { u32x2 t = {r[0], r[1]}; return __builtin_bit_cast(s16x4, t); }
__device__ __forceinline__ s16x4 hi4(u32x4 r) { u32x2 t = {r[2], r[3]}; return __builtin_bit_cast(s16x4, t); }
__device__ __forceinline__ s16x8 bc8(u32x4 r) { return __builtin_bit_cast(s16x8, r); }

// raw v_exp_f32: scores are bounded (|s|<~8), no denormal fixups needed.
__device__ __forceinline__ float fexp2(float x) {
  float r;
  asm("v_exp_f32 %0, %1" : "=v"(r) : "v"(x));
  return r;
}

#define XLS 264   // proj LDS row stride (256 + 8 pad)

// ---------------- Kernel A: fused QKV projection (64-col, R7/R13-verified) ----------------
// QT: [B][N][32] bf16 row-contiguous.
// KT: LANE-ORDERED [B][jt=128][kh=2][lane=64][8] bf16.
// Vm: LANE-ORDERED [B][jt=128][cq=8][kh=2][lane=64][8] bf16 (k-slot bijection).
__global__ __launch_bounds__(256)
void proj_kernel(const float* __restrict__ x,
                 const float* __restrict__ Wq, const float* __restrict__ bq,
                 const float* __restrict__ Wk, const float* __restrict__ bk,
                 const float* __restrict__ Wv, const float* __restrict__ bv,
                 unsigned short* __restrict__ QT,
                 unsigned short* __restrict__ KT,
                 unsigned short* __restrict__ Vm) {
  __shared__ unsigned short Xl[64 * XLS];
  const int tid = threadIdx.x;
  const int b   = blockIdx.y;
  const int n0  = blockIdx.x * 64;

  {
    const int n4 = (tid & 15) * 4;
    int c = tid >> 4;
    const float* xp = x + (size_t)(b * CC + c) * NN + n0 + n4;
    #pragma unroll
    for (int it = 0; it < 16; ++it) {
      f32x4 v = *reinterpret_cast<const f32x4*>(xp);
      #pragma unroll
      for (int e = 0; e < 4; ++e)
        Xl[(n4 + e) * XLS + c] = f2bf(v[e]);
      c += 16; xp += (size_t)16 * NN;
    }
  }
  __syncthreads();

  const int wave = tid >> 6;
  const int lane = tid & 63;
  const int l16  = lane & 15;
  const int g    = lane >> 4;
  const float qscale = 0.0901684400555602f;  // log2(e)/16

  const float* wrowp[5];
  float wsc[5];
  #pragma unroll
  for (int rt = 0; rt < 5; ++rt) {
    const int R0 = (wave * 5 + rt) * 16;
    const int R  = R0 + l16;
    if (R0 < 32)      { wrowp[rt] = Wq + R * CC;        wsc[rt] = qscale; }
    else if (R0 < 64) { wrowp[rt] = Wk + (R - 32) * CC; wsc[rt] = 1.0f; }
    else              { wrowp[rt] = Wv + (R - 64) * CC; wsc[rt] = 1.0f; }
  }

  f32x4 acc[5][4];
  #pragma unroll
  for (int rt = 0; rt < 5; ++rt)
    #pragma unroll
    for (int nt = 0; nt < 4; ++nt) acc[rt][nt] = (f32x4){0.f, 0.f, 0.f, 0.f};

  for (int k0 = 0; k0 < CC; k0 += 32) {
    s16x4 xb[4][2];
    #pragma unroll
    for (int nt = 0; nt < 4; ++nt) {
      const unsigned short* p = &Xl[(l16 + 16 * nt) * XLS + k0 + 8 * g];
      u32x4 raw = *reinterpret_cast<const u32x4*>(p);
      xb[nt][0] = lo4(raw);
      xb[nt][1] = hi4(raw);
    }
    #pragma unroll
    for (int rt = 0; rt < 5; ++rt) {
      const float* wp = wrowp[rt] + k0 + 8 * g;
      f32x4 w0 = *reinterpret_cast<const f32x4*>(wp);
      f32x4 w1 = *reinterpret_cast<const f32x4*>(wp + 4);
      const float sc = wsc[rt];
      s16x4 wa0, wa1;
      #pragma unroll
      for (int e = 0; e < 4; ++e) {
        wa0[e] = (short)f2bf(w0[e] * sc);
        wa1[e] = (short)f2bf(w1[e] * sc);
      }
      #pragma unroll
      for (int nt = 0; nt < 4; ++nt) {
        acc[rt][nt] = mfma16(wa0, xb[nt][0], acc[rt][nt]);
        acc[rt][nt] = mfma16(wa1, xb[nt][1], acc[rt][nt]);
      }
    }
  }

  #pragma unroll
  for (int rt = 0; rt < 5; ++rt) {
    const int R0 = (wave * 5 + rt) * 16;
    float bias_r[4];
    {
      const float* bp; float bsc;
      if (R0 < 32)      { bp = bq + R0;      bsc = qscale; }
      else if (R0 < 64) { bp = bk + R0 - 32; bsc = 1.0f; }
      else              { bp = bv + R0 - 64; bsc = 1.0f; }
      #pragma unroll
      for (int r = 0; r < 4; ++r) bias_r[r] = bp[4 * g + r] * bsc;
    }
    #pragma unroll
    for (int nt = 0; nt < 4; ++nt) {
      const int n = n0 + nt * 16 + l16;
      float v0 = acc[rt][nt][0] + bias_r[0];
      float v1 = acc[rt][nt][1] + bias_r[1];
      float v2 = acc[rt][nt][2] + bias_r[2];
      float v3 = acc[rt][nt][3] + bias_r[3];
      if (R0 < 32) {
        u32x2 pk = { (unsigned)f2bf(v0) | ((unsigned)f2bf(v1) << 16),
                     (unsigned)f2bf(v2) | ((unsigned)f2bf(v3) << 16) };
        unsigned short* dst = QT + ((size_t)b * NN + n) * DQ + R0 + 4 * g;
        *reinterpret_cast<u32x2*>(dst) = pk;
      } else if (R0 < 64) {
        const int d0     = R0 - 32 + 4 * g;
        const int kh     = d0 >> 4;
        const int g2v    = (d0 >> 3) & 1;
        const int e0     = d0 & 7;
        const int jt     = n >> 5;
        const int lane_t = (n & 31) + 32 * g2v;
        u32x2 pk = { (unsigned)f2bf(v0) | ((unsigned)f2bf(v1) << 16),
                     (unsigned)f2bf(v2) | ((unsigned)f2bf(v3) << 16) };
        unsigned short* kd = KT + (((size_t)(b * 128 + jt) * 2 + kh) * 64 + lane_t) * 8 + e0;
        *reinterpret_cast<u32x2*>(kd) = pk;
      } else {
        const int c0  = R0 - 64 + 4 * g;
        const int cq  = c0 >> 5;
        const int cl  = c0 & 31;
        const int jt  = (n0 + nt * 16) >> 5;
        const int kh  = nt & 1;
        const int g2v = (l16 >> 2) & 1;
        const int e   = (l16 & 3) | (((l16 >> 3) & 1) << 2);
        unsigned short* vd = Vm
          + ((((size_t)(b * 128 + jt) * 8 + cq) * 2 + kh) * 64 + (cl + 32 * g2v)) * 8 + e;
        vd[0]  = f2bf(v0);
        vd[8]  = f2bf(v1);
        vd[16] = f2bf(v2);
        vd[24] = f2bf(v3);
      }
    }
  }
}

// ---------------- Kernel B: flash attention, Q=32/wave, 2x-redundant softmax ----------------
// 512 blocks x 512 threads; block = 32 q; 8 waves = jq(2) x jsub(2) x cs(2).
// Wave: 32 q x 128 c x 32 j-tiles (quarter of j). R16's iter pattern, 8 V loads.
// Softmax redundancy 4x -> 2x (block exp2 instrs halve). 2-stage end merge
// (jsub pairs then jq pairs), loop stays barrier-free.

#define SM16(SS, L, P0_, P1_) { \
  const float p0=fexp2(SS[0]),  p1=fexp2(SS[1]),  p2=fexp2(SS[2]),  p3=fexp2(SS[3]); \
  const float p4=fexp2(SS[4]),  p5=fexp2(SS[5]),  p6=fexp2(SS[6]),  p7=fexp2(SS[7]); \
  const float p8=fexp2(SS[8]),  p9=fexp2(SS[9]),  pa=fexp2(SS[10]), pb=fexp2(SS[11]); \
  const float pc=fexp2(SS[12]), pd=fexp2(SS[13]), pe=fexp2(SS[14]), pf=fexp2(SS[15]); \
  L += (((p0+p1)+(p2+p3)) + ((p4+p5)+(p6+p7))) + (((p8+p9)+(pa+pb)) + ((pc+pd)+(pe+pf))); \
  unsigned q0,q1,q2,q3,q4,q5,q6,q7; \
  asm("v_cvt_pk_bf16_f32 %0, %1, %2" : "=v"(q0) : "v"(p0), "v"(p1)); \
  asm("v_cvt_pk_bf16_f32 %0, %1, %2" : "=v"(q1) : "v"(p2), "v"(p3)); \
  asm("v_cvt_pk_bf16_f32 %0, %1, %2" : "=v"(q2) : "v"(p4), "v"(p5)); \
  asm("v_cvt_pk_bf16_f32 %0, %1, %2" : "=v"(q3) : "v"(p6), "v"(p7)); \
  asm("v_cvt_pk_bf16_f32 %0, %1, %2" : "=v"(q4) : "v"(p8), "v"(p9)); \
  asm("v_cvt_pk_bf16_f32 %0, %1, %2" : "=v"(q5) : "v"(pa), "v"(pb)); \
  asm("v_cvt_pk_bf16_f32 %0, %1, %2" : "=v"(q6) : "v"(pc), "v"(pd)); \
  asm("v_cvt_pk_bf16_f32 %0, %1, %2" : "=v"(q7) : "v"(pe), "v"(pf)); \
  u32x4 _w0 = {q0,q1,q2,q3}, _w1 = {q4,q5,q6,q7}; \
  P0_ = bc8(_w0); P1_ = bc8(_w1); }

#define LOADK_IMPL(T, KA, KB) { \
  const int _tk = ((T) < 32) ? (T) : 31; \
  const size_t _o = (size_t)_tk * 1024; \
  KA = *(const u32x4*)(Kb + _o); \
  KB = *(const u32x4*)(Kb + _o + 512); }

#define LOADV_IMPL(T, V0, V1, V2, V3, V4, V5, V6, V7) { \
  const int _tv = ((T) < 32) ? (T) : 31; \
  const size_t _o = (size_t)_tv * 8192; \
  V0 = *(const u32x4*)(Vb + _o); \
  V1 = *(const u32x4*)(Vb + _o + 512); \
  V2 = *(const u32x4*)(Vb + _o + 1024); \
  V3 = *(const u32x4*)(Vb + _o + 1536); \
  V4 = *(const u32x4*)(Vb + _o + 2048); \
  V5 = *(const u32x4*)(Vb + _o + 2560); \
  V6 = *(const u32x4*)(Vb + _o + 3072); \
  V7 = *(const u32x4*)(Vb + _o + 3584); }

// iter T: prefetch T+1 into next set, QK(T), softmax, PV(T)
#define ITER_IMPL(T, KA, KB, V0, V1, V2, V3, V4, V5, V6, V7, \
                     NKA, NKB, NV0, NV1, NV2, NV3, NV4, NV5, NV6, NV7) { \
  LOADK_IMPL((T) + 1, NKA, NKB); \
  LOADV_IMPL((T) + 1, NV0, NV1, NV2, NV3, NV4, NV5, NV6, NV7); \
  f32x16 ss = mfma32b(bc8(KA), qf0, zz16); \
  ss = mfma32b(bc8(KB), qf1, ss); \
  s16x8 P0, P1; \
  SM16(ss, l, P0, P1); \
  o0 = mfma32b(bc8(V0), P0, o0); \
  o0 = mfma32b(bc8(V1), P1, o0); \
  o1 = mfma32b(bc8(V2), P0, o1); \
  o1 = mfma32b(bc8(V3), P1, o1); \
  o2 = mfma32b(bc8(V4), P0, o2); \
  o2 = mfma32b(bc8(V5), P1, o2); \
  o3 = mfma32b(bc8(V6), P0, o3); \
  o3 = mfma32b(bc8(V7), P1, o3); \
}
#define ITER(T, SETC, SETN) ITER_IMPL(T, SETC, SETN)

#define SET_A kA0, kB0, va0, va1, va2, va3, va4, va5, va6, va7
#define SET_B kA1, kB1, vb0, vb1, vb2, vb3, vb4, vb5, vb6, vb7

// merge LDS layout: stage1 region [jq][cs][ct][r][lane] (16384 f),
// stage2 reuses [cs][ct][r][lane] (8192 f); l slots at 16384.
#define S1IDX(CT, R) ((((jq * 2 + cs) * 4 + (CT)) * 16 + (R)) * 64 + lane)
#define S2IDX(CT, R) (((cs * 4 + (CT)) * 16 + (R)) * 64 + lane)
#define LOFF 16384

#define PUB1_CT(CT, OV) { \
  _Pragma("unroll") \
  for (int r = 0; r < 16; ++r) fb[S1IDX(CT, r)] = OV[r]; }
#define ABS1_CT(CT, OV) { \
  _Pragma("unroll") \
  for (int r = 0; r < 16; ++r) OV[r] += fb[S1IDX(CT, r)]; }
#define PUB2_CT(CT, OV) { \
  _Pragma("unroll") \
  for (int r = 0; r < 16; ++r) fb[S2IDX(CT, r)] = OV[r]; }
#define FIN_CT(CT, OV) { \
  _Pragma("unroll") \
  for (int r = 0; r < 16; ++r) { \
    const float oB = fb[S2IDX(CT, r)]; \
    const int   c  = cs * 128 + (CT) * 32 + (r & 3) + 8 * (r >> 2) + 4 * g2; \
    const size_t adr = ((size_t)b * CC + c) * NN + i; \
    out[adr] = ga * (OV[r] + oB) + x[adr]; } }

__global__ __launch_bounds__(512)
void attn_kernel(const unsigned short* __restrict__ QT,
                 const unsigned short* __restrict__ KT,
                 const unsigned short* __restrict__ Vm,
                 const float* __restrict__ x,
                 const float* __restrict__ gamma,
                 float* __restrict__ out) {
  extern __shared__ float fb[];   // 16384 + 128 floats

  const int tid  = threadIdx.x;
  const int wave = tid >> 6;
  const int jq   = wave >> 2;        // j-half
  const int jsub = (wave >> 1) & 1;  // j-quarter within half
  const int cs   = wave & 1;         // 128-channel slice
  const int lane = tid & 63;
  const int l31  = lane & 31;
  const int g2   = lane >> 5;
  const int jquarter = jq * 2 + jsub;

  // XCD swizzle: gid%8 -> XCD; one batch per XCD pair; xt 0..127 per batch
  const int gid = blockIdx.x;
  const int rr  = gid & 7;
  const int qq  = gid >> 3;
  const int b   = rr >> 1;
  const int xt  = (qq << 1) | (rr & 1);
  const int ibase = xt * 32;
  const float gamma0 = gamma[0];

  // Q frags (32 q rows)
  const unsigned short* Qb = QT + ((size_t)b * NN + ibase + l31) * DQ;
  const s16x8 qf0 = bc8(*(const u32x4*)(Qb + 8 * g2));
  const s16x8 qf1 = bc8(*(const u32x4*)(Qb + 16 + 8 * g2));

  f32x16 o0, o1, o2, o3, zz16;
  #pragma unroll
  for (int r = 0; r < 16; ++r) { o0[r] = 0.f; o1[r] = 0.f; o2[r] = 0.f; o3[r] = 0.f; zz16[r] = 0.f; }
  float l = 0.f;

  const unsigned short* Kb = KT + (size_t)(b * 128 + jquarter * 32) * 1024 + lane * 8;
  const unsigned short* Vb = Vm + ((size_t)(b * 128 + jquarter * 32) * 8 + cs * 4) * 1024 + lane * 8;

  u32x4 kA0, kB0, va0, va1, va2, va3, va4, va5, va6, va7;
  u32x4 kA1, kB1, vb0, vb1, vb2, vb3, vb4, vb5, vb6, vb7;

  // prologue: tile 0 -> A
  LOADK_IMPL(0, kA0, kB0);
  LOADV_IMPL(0, va0, va1, va2, va3, va4, va5, va6, va7);

  #pragma unroll 1
  for (int tt = 0; tt < 16; ++tt) {
    const int t = 2 * tt;
    ITER(t,     SET_A, SET_B);
    ITER(t + 1, SET_B, SET_A);
  }

  // fold the two g2 halves of the denominator
  l += __shfl_xor(l, 32);

  // ---- stage 1: jsub=1 publishes, jsub=0 absorbs ----
  if (jsub == 1) {
    PUB1_CT(0, o0);
    PUB1_CT(1, o1);
    PUB1_CT(2, o2);
    PUB1_CT(3, o3);
    if (cs == 0 && g2 == 0) fb[LOFF + jq * 32 + l31] = l;
  }
  __syncthreads();
  if (jsub == 0) {
    ABS1_CT(0, o0);
    ABS1_CT(1, o1);
    ABS1_CT(2, o2);
    ABS1_CT(3, o3);
    l += fb[LOFF + jq * 32 + l31];
    // ---- stage 2 publish: jq=1 ----
    if (jq == 1) {
      PUB2_CT(0, o0);
      PUB2_CT(1, o1);
      PUB2_CT(2, o2);
      PUB2_CT(3, o3);
      if (cs == 0 && g2 == 0) fb[LOFF + 64 + l31] = l;
    }
  }
  __syncthreads();
  if (jsub == 0 && jq == 0) {
    const float lB = fb[LOFF + 64 + l31];
    const float ga = gamma0 / (l + lB);
    const int i = ibase + l31;
    FIN_CT(0, o0);
    FIN_CT(1, o1);
    FIN_CT(2, o2);
    FIN_CT(3, o3);
  }
}

extern "C" void kernel_launch(void* const* d_in, const int* in_sizes, int n_in,
                              void* d_out, int out_size, void* d_ws, size_t ws_size,
                              hipStream_t stream) {
  const float* x     = (const float*)d_in[0];
  const float* Wq    = (const float*)d_in[1];
  const float* bq    = (const float*)d_in[2];
  const float* Wk    = (const float*)d_in[3];
  const float* bk    = (const float*)d_in[4];
  const float* Wv    = (const float*)d_in[5];
  const float* bv    = (const float*)d_in[6];
  const float* gamma = (const float*)d_in[7];
  float* out = (float*)d_out;

  unsigned short* QT = (unsigned short*)d_ws;
  unsigned short* KT = QT + (size_t)NB * NN * DQ;
  unsigned short* Vm = KT + (size_t)NB * NN * DQ;

  const int ldsB = (16384 + 128) * 4;   // 66048 B dynamic LDS for the 2-stage merge
  static bool attr_set = false;
  if (!attr_set) {
    hipFuncSetAttribute((const void*)attn_kernel,
                        hipFuncAttributeMaxDynamicSharedMemorySize, ldsB);
    attr_set = true;
  }

  dim3 gridP(64, NB), blkP(256);
  proj_kernel<<<gridP, blkP, 0, stream>>>(x, Wq, bq, Wk, bk, Wv, bv, QT, KT, Vm);
  attn_kernel<<<512, 512, ldsB, stream>>>(QT, KT, Vm, x, gamma, out);
}